// Round 4
// baseline (426.991 us; speedup 1.0000x reference)
//
#include <hip/hip_runtime.h>
#include <hip/hip_bf16.h>

// Keep every fp op matching numpy/jax f32 op-by-op rounding (no fma fusion):
#pragma clang fp contract(off)

#define NUM_CLASSES 100
#define B_DIM 8
#define N_DIM 32768
#define TOPK_K 1024
#define ROW_F 105
#define CONF_THRE_F 0.001f
#define NMS_THRE_F 0.65f
#define OFFSET_F 241.0f   // MAX_DIM + 1
#define HBINS 8192        // key bits 52..40 (= ou bits 30..18), 0 if invalid

typedef unsigned long long u64;
typedef unsigned int u32;

__device__ __forceinline__ u64 shfl64(u64 v, int src) {
    int lo = __shfl((int)(v & 0xFFFFFFFFull), src);
    int hi = __shfl((int)(v >> 32), src);
    return ((u64)(u32)hi << 32) | (u32)lo;
}

__device__ __forceinline__ u32 key_bin1(u64 k) {
    return ((k >> 53) & 1ull) ? (u32)((k >> 40) & 0x1FFFull) : 0u;
}

// ---------------------------------------------------------------------------
// Kernel 1: one wave per row, ONE aligned float4 load per lane (27 lanes),
// u32 bit-order class argmax, packed key + global histogram.
// key (54 bits): [ou(32) << 22] | [(32767-n)(15) << 7] | class(7)
// ---------------------------------------------------------------------------
template <int P, int WV>
__device__ __forceinline__ float getpos(const float4& v) {
    constexpr int sl = (P + WV) / 4;
    constexpr int se = (P + WV) % 4;
    float c = (se == 0) ? v.x : (se == 1) ? v.y : (se == 2) ? v.z : v.w;
    return __shfl(c, sl);
}

template <int WV>
__device__ __forceinline__ void decode_wave(const float* __restrict__ pred,
                                            u64* __restrict__ keys,
                                            u32* __restrict__ hist,
                                            int r, int lane) {
    const float* pal = pred + (size_t)r * ROW_F - WV;   // 16B-aligned window
    float4 v = make_float4(0.f, 0.f, 0.f, 0.f);
    if (lane < 27) v = reinterpret_cast<const float4*>(pal)[lane];

    // box floats (positions 0..4) via static-component shfl from lanes 0..1
    float cx  = getpos<0, WV>(v);
    float cy  = getpos<1, WV>(v);
    float w   = getpos<2, WV>(v);
    float h   = getpos<3, WV>(v);
    float obj = getpos<4, WV>(v);

    // per-lane class max: bits order == float order (all class scores >= 0);
    // strict '>' with e ascending => tie keeps lowest class (= max cc).
    const float fe[4] = {v.x, v.y, v.z, v.w};
    u32 bb = 0u, cc = 0u;
#pragma unroll
    for (int e = 0; e < 4; ++e) {
        const int p = (lane << 2) + e - WV;
        u32 bf = __float_as_uint(fe[e]) | 0x80000000u;
        bool okc = (p >= 5) && (p <= 104);
        u32 cf = (u32)(104 + WV - (lane << 2) - e);      // 99 - class
        if (okc && bf > bb) { bb = bf; cc = cf; }
    }
    const u32 bb0 = bb;
#pragma unroll
    for (int off = 32; off; off >>= 1) {
        u32 o = (u32)__shfl_xor((int)bb, off);
        bb = (o > bb) ? o : bb;
    }
    u32 cz = (bb0 == bb) ? cc : 0u;   // cc>=4 for real classes, 0 = "not max"
#pragma unroll
    for (int off = 32; off; off >>= 1) {
        u32 o = (u32)__shfl_xor((int)cz, off);
        cz = (o > cz) ? o : cz;
    }

    if (lane == 0) {
        float cmax = __uint_as_float(bb & 0x7FFFFFFFu);
        int cls = 99 - (int)cz;
        float score = obj * cmax;                    // reference op order
        bool valid = (score * cmax) >= CONF_THRE_F;
        float mval = valid ? score : -1.0f;
        u32 u  = __float_as_uint(mval);
        u32 ou = (u & 0x80000000u) ? ~u : (u | 0x80000000u);
        u64 key = ((u64)ou << 22) |
                  ((u64)(u32)((r & (N_DIM - 1)) ^ (N_DIM - 1)) << 7) |
                  (u64)cls;
        keys[r] = key;
        u32 bin = (ou & 0x80000000u) ? ((ou >> 18) & 0x1FFFu) : 0u;
        atomicAdd(&hist[((u32)r >> 15) * HBINS + bin], 1u);
    }
}

__global__ __launch_bounds__(256) void decode_kernel(const float* __restrict__ pred,
                                                     u64* __restrict__ keys,
                                                     u32* __restrict__ hist) {
    const int lane = threadIdx.x & 63;
    const int wid  = threadIdx.x >> 6;
    const int r    = (blockIdx.x << 2) + wid;   // WV = r % 4 == wid
    switch (wid) {
        case 0: decode_wave<0>(pred, keys, hist, r, lane); break;
        case 1: decode_wave<1>(pred, keys, hist, r, lane); break;
        case 2: decode_wave<2>(pred, keys, hist, r, lane); break;
        default: decode_wave<3>(pred, keys, hist, r, lane); break;
    }
}

// ---------------------------------------------------------------------------
// wave-0 suffix scan over 8192-bin LDS hist (rotated reads: conflict-free).
// ---------------------------------------------------------------------------
__device__ __forceinline__ void scan_hist(const u32* h, u32 target, u32* binT_out) {
    const int lane = threadIdx.x & 63;
    const u32* hl = h + lane * 128;
    u32 partial = 0;
    for (int k = 0; k < 128; ++k) partial += hl[(k + lane) & 127];
    u32 v = partial;
#pragma unroll
    for (int off = 1; off < 64; off <<= 1) {
        u32 o = __shfl_down(v, off);
        if (lane + off < 64) v += o;
    }
    u32 above = v - partial;                 // bins in strictly-higher lanes
    if (above < target && above + partial >= target) {
        u32 cum = above;
        int bin = lane * 128 + 127;
        for (;; --bin) {
            cum += h[bin];
            if (cum >= target) break;
        }
        *binT_out = (u32)bin;
    }
}

// ---------------------------------------------------------------------------
// Kernel 2: load hist -> scan -> ONE compaction pass -> enumeration rank ->
// class-sparse mask NMS -> output. One 1024-thread block per batch.
// ---------------------------------------------------------------------------
__global__ __launch_bounds__(1024) void selnms_kernel(const float* __restrict__ pred,
                                                      const u64* __restrict__ keys,
                                                      const u32* __restrict__ hist,
                                                      float* __restrict__ out) {
    const int b    = blockIdx.x;
    const int tid  = threadIdx.x;
    const int wid  = tid >> 6;
    const int lane = tid & 63;

    __shared__ u64 sel[TOPK_K];                    // 8 KB, rank-ordered keys
    alignas(16) __shared__ char SC[32768];         // phase-reused region
    __shared__ u64 keepm_s[16];
    __shared__ u32 binT_s, cnt_s;
    __shared__ u32 cls_cnt[104], cls_start[104], cls_fill[104];

    u32* hist_s = (u32*)SC;                        // phase A: 32 KB
    u64* cand   = (u64*)SC;                        // phase B: 2048 keys (16 KB)
    float* sx1 = (float*)SC;                       // phase C (NMS):
    float* sy1 = (float*)(SC + 4096);
    float* sx2 = (float*)(SC + 8192);
    float* sy2 = (float*)(SC + 12288);
    float* sar = (float*)(SC + 16384);
    unsigned short* items = (unsigned short*)(SC + 20480);

    const u64* K = keys + (size_t)b * N_DIM;

    if (tid < 100) { cls_cnt[tid] = 0u; cls_fill[tid] = 0u; }
    if (tid == 0) cnt_s = 0u;
    for (int i = tid; i < HBINS; i += 1024) hist_s[i] = hist[b * HBINS + i];
    __syncthreads();

    if (wid == 0) scan_hist(hist_s, TOPK_K, &binT_s);
    __syncthreads();
    const u32 binT = binT_s;
    __syncthreads();                               // hist_s dead -> cand

    // ---- single compaction pass: bin >= binT (C in [1024, ~1536]) ----
    for (int n = tid * 2; n < N_DIM; n += 2048) {
        ulonglong2 k2 = *reinterpret_cast<const ulonglong2*>(K + n);
        if (key_bin1(k2.x) >= binT) {
            u32 p = atomicAdd(&cnt_s, 1u);
            if (p < 2048u) cand[p] = k2.x;
        }
        if (key_bin1(k2.y) >= binT) {
            u32 p = atomicAdd(&cnt_s, 1u);
            if (p < 2048u) cand[p] = k2.y;
        }
    }
    __syncthreads();
    int C = (int)cnt_s; if (C > 2048) C = 2048;
    if (tid == 0 && (C & 1)) cand[C] = 0ull;       // pad to even
    const int CP = (C + 1) & ~1;
    __syncthreads();

    // ---- enumeration rank (keys unique -> ranks unique; rank 0 = largest) ----
    u64 my0 = (tid < C) ? cand[tid] : 0ull;
    bool h1 = (tid + 1024) < C;
    u64 my1 = h1 ? cand[tid + 1024] : 0ull;
    u32 r0 = 0, r1 = 0;
    if (!h1) {
        for (int i = 0; i < CP; i += 2) {
            ulonglong2 kk2 = *(const ulonglong2*)(cand + i);
            r0 += (kk2.x > my0) + (kk2.y > my0);
        }
    } else {
        for (int i = 0; i < CP; i += 2) {
            ulonglong2 kk2 = *(const ulonglong2*)(cand + i);
            r0 += (kk2.x > my0) + (kk2.y > my0);
            r1 += (kk2.x > my1) + (kk2.y > my1);
        }
    }
    if (tid < C && r0 < TOPK_K) sel[r0] = my0;
    if (h1 && r1 < TOPK_K) sel[r1] = my1;
    __syncthreads();                               // cand dead -> NMS arrays

    // ---- decode rank-tid box ----
    u64 key = sel[tid];
    int lab = (int)(key & 0x7Full);
    int n   = (N_DIM - 1) - (int)((key >> 7) & (u64)(N_DIM - 1));
    u32 ou  = (u32)(key >> 22);
    u32 ob  = (ou & 0x80000000u) ? (ou & 0x7FFFFFFFu) : ~ou;
    float score = __uint_as_float(ob);
    bool validk = (score >= 0.0f);

    const float* row = pred + ((size_t)b * N_DIM + n) * ROW_F;
    float cx = row[0], cy = row[1], w = row[2], h = row[3];
    float x1 = cx - w * 0.5f, y1 = cy - h * 0.5f;
    float x2 = w + x1,        y2 = h + y1;         // reference: xy2 = wh + xy1
    float off = (float)lab * OFFSET_F;
    float nx1 = x1 + off, ny1 = y1 + off, nx2 = x2 + off, ny2 = y2 + off;
    float area = (nx2 - nx1) * (ny2 - ny1);

    sx1[tid] = nx1; sy1[tid] = ny1; sx2[tid] = nx2; sy2[tid] = ny2; sar[tid] = area;
    atomicAdd(&cls_cnt[lab], 1u);
    __syncthreads();
    if (tid == 0) {
        u32 s = 0;
        for (int c = 0; c < 100; ++c) { cls_start[c] = s; s += cls_cnt[c]; }
    }
    __syncthreads();
    {
        u32 p = cls_start[lab] + atomicAdd(&cls_fill[lab], 1u);
        items[p] = (unsigned short)tid;
    }
    __syncthreads();

    // ---- suppression-mask column, same-class partners only (~10 IoUs) ----
    // Cross-class IoU is exactly 0 (class offset 241 >= extent bound 231).
    u64 m0=0,m1=0,m2=0,m3=0,m4=0,m5=0,m6=0,m7=0,
        m8=0,m9=0,m10=0,m11=0,m12=0,m13=0,m14=0,m15=0;
    {
        const int s0 = (int)cls_start[lab];
        const int e0 = s0 + (int)cls_cnt[lab];
        for (int p = s0; p < e0; ++p) {
            int i = (int)items[p];
            if (i == tid) continue;
            float ix1 = fmaxf(sx1[i], nx1), iy1 = fmaxf(sy1[i], ny1);
            float ix2 = fminf(sx2[i], nx2), iy2 = fminf(sy2[i], ny2);
            float iw = fmaxf(ix2 - ix1, 0.0f), ih = fmaxf(iy2 - iy1, 0.0f);
            float inter = iw * ih;
            float iou = inter / (sar[i] + area - inter + 1e-12f);
            if (iou > NMS_THRE_F) {
                u64 bit = 1ull << (i & 63);
                int ch = i >> 6;
                m0  |= (ch == 0)  ? bit : 0ull;  m1  |= (ch == 1)  ? bit : 0ull;
                m2  |= (ch == 2)  ? bit : 0ull;  m3  |= (ch == 3)  ? bit : 0ull;
                m4  |= (ch == 4)  ? bit : 0ull;  m5  |= (ch == 5)  ? bit : 0ull;
                m6  |= (ch == 6)  ? bit : 0ull;  m7  |= (ch == 7)  ? bit : 0ull;
                m8  |= (ch == 8)  ? bit : 0ull;  m9  |= (ch == 9)  ? bit : 0ull;
                m10 |= (ch == 10) ? bit : 0ull;  m11 |= (ch == 11) ? bit : 0ull;
                m12 |= (ch == 12) ? bit : 0ull;  m13 |= (ch == 13) ? bit : 0ull;
                m14 |= (ch == 14) ? bit : 0ull;  m15 |= (ch == 15) ? bit : 0ull;
            }
        }
    }

    // ---- greedy scan, 16 chunks; serial work only on conflicted lanes ----
    bool supp = false, keepb = false;
#define CHUNK_STEP(c, mc)                                                     \
    {                                                                         \
        if (wid == (c)) {                                                     \
            u64 W  = (mc);                                                    \
            u64 vm = __ballot(validk && !supp);                               \
            u64 S  = __ballot(W != 0ull);                                     \
            u64 km = vm & ~S;                                                 \
            u64 suppm = 0ull, mm = S;                                         \
            while (mm) {                                                      \
                int i = __builtin_ctzll(mm); mm &= mm - 1ull;                 \
                u64 Wi = shfl64(W, i);                                        \
                if (((vm >> i) & 1ull) && !((suppm >> i) & 1ull)) {           \
                    km |= 1ull << i; suppm |= Wi;                             \
                }                                                             \
            }                                                                 \
            keepb = ((km >> lane) & 1ull) != 0ull;                            \
            if (lane == 0) keepm_s[(c)] = km;                                 \
        }                                                                     \
        __syncthreads();                                                      \
        if (wid > (c) && ((mc) & keepm_s[(c)])) supp = true;                  \
    }
    CHUNK_STEP(0, m0)   CHUNK_STEP(1, m1)   CHUNK_STEP(2, m2)   CHUNK_STEP(3, m3)
    CHUNK_STEP(4, m4)   CHUNK_STEP(5, m5)   CHUNK_STEP(6, m6)   CHUNK_STEP(7, m7)
    CHUNK_STEP(8, m8)   CHUNK_STEP(9, m9)   CHUNK_STEP(10, m10) CHUNK_STEP(11, m11)
    CHUNK_STEP(12, m12) CHUNK_STEP(13, m13) CHUNK_STEP(14, m14) CHUNK_STEP(15, m15)
#undef CHUNK_STEP

    float keepf = keepb ? 1.0f : 0.0f;
    float2* o2 = (float2*)(out + ((size_t)b * TOPK_K + tid) * 6);
    o2[0] = make_float2(x1 * keepf, y1 * keepf);
    o2[1] = make_float2(x2 * keepf, y2 * keepf);
    o2[2] = make_float2(score * keepf, (float)lab * keepf);
}

// ---------------------------------------------------------------------------
extern "C" void kernel_launch(void* const* d_in, const int* in_sizes, int n_in,
                              void* d_out, int out_size, void* d_ws, size_t ws_size,
                              hipStream_t stream) {
    const float* pred = (const float*)d_in[0];
    float* out = (float*)d_out;

    u64* keys = (u64*)d_ws;                                  // 2 MB
    u32* hist = (u32*)((char*)d_ws + (2u << 20));            // 256 KB

    hipMemsetAsync(hist, 0, B_DIM * HBINS * sizeof(u32), stream);
    decode_kernel<<<(B_DIM * N_DIM) / 4, 256, 0, stream>>>(pred, keys, hist);
    selnms_kernel<<<B_DIM, 1024, 0, stream>>>(pred, keys, hist, out);
}

// Round 5
// 103.964 us; speedup vs baseline: 4.1071x; 4.1071x over previous
//
#include <hip/hip_runtime.h>
#include <hip/hip_bf16.h>

// Keep every fp op matching numpy/jax f32 op-by-op rounding (no fma fusion):
#pragma clang fp contract(off)

#define NUM_CLASSES 100
#define B_DIM 8
#define N_DIM 32768
#define TOPK_K 1024
#define ROW_F 105
#define CONF_THRE_F 0.001f
#define NMS_THRE_F 0.65f
#define OFFSET_F 241.0f   // MAX_DIM + 1
#define CAND_CAP 1280     // >= C (two-level select gives C ~= 1030)

typedef unsigned long long u64;
typedef unsigned int u32;

__device__ __forceinline__ u64 shfl64(u64 v, int src) {
    int lo = __shfl((int)(v & 0xFFFFFFFFull), src);
    int hi = __shfl((int)(v >> 32), src);
    return ((u64)(u32)hi << 32) | (u32)lo;
}

// key layout (54 bits): [ou(32) << 22] | [(32767-n)(15) << 7] | class(7)
__device__ __forceinline__ u32 key_bin1(u64 k) {   // ou bits 30..18, 0 if invalid
    return ((k >> 53) & 1ull) ? (u32)((k >> 40) & 0x1FFFull) : 0u;
}
__device__ __forceinline__ u32 key_bin2(u64 k) {   // ou bits 17..5
    return (u32)((k >> 27) & 0x1FFFull);
}

// ---------------------------------------------------------------------------
// Kernel 1: decode. LDS-staged 64-row chunks (coalesced float4), then
// thread-per-row scan from LDS. No shfl, no atomics. 256 rows per block.
// ---------------------------------------------------------------------------
__global__ __launch_bounds__(256) void decode_kernel(const float* __restrict__ pred,
                                                     u64* __restrict__ keys) {
    __shared__ float buf[64 * ROW_F];            // 26880 B
    const int tid = threadIdx.x;
    const int rb  = blockIdx.x << 8;             // 256 rows per block

    for (int c = 0; c < 4; ++c) {
        const int r0 = rb + (c << 6);
        const float4* src = reinterpret_cast<const float4*>(pred + (size_t)r0 * ROW_F);
        float4* dst = reinterpret_cast<float4*>(buf);
        for (int i = tid; i < (64 * ROW_F / 4); i += 256) dst[i] = src[i];
        __syncthreads();
        if (tid < 64) {
            const float* R = buf + tid * ROW_F;
            float obj = R[4];
            u32 bb = 0u; int cls = 0;
#pragma unroll 10
            for (int k = 5; k < 105; ++k) {
                // all class scores >= 0: bit order == float order; strict '>'
                // with k ascending keeps the FIRST max (== jnp.argmax).
                u32 bf = __float_as_uint(R[k]) | 0x80000000u;
                if (bf > bb) { bb = bf; cls = k - 5; }
            }
            float cmax = __uint_as_float(bb & 0x7FFFFFFFu);
            float score = obj * cmax;                    // reference op order
            bool valid = (score * cmax) >= CONF_THRE_F;
            float mval = valid ? score : -1.0f;
            u32 u  = __float_as_uint(mval);
            u32 ou = (u & 0x80000000u) ? ~u : (u | 0x80000000u);
            int r = r0 + tid;
            u64 key = ((u64)ou << 22) |
                      ((u64)(u32)((r & (N_DIM - 1)) ^ (N_DIM - 1)) << 7) |
                      (u64)cls;
            keys[r] = key;
        }
        __syncthreads();
    }
}

// ---------------------------------------------------------------------------
// wave-0 suffix scan over 8192-bin LDS hist (rotated reads: conflict-free).
// binT: count(bin > binT) < target <= count(bin >= binT). c1_out = strictly
// above binT.
// ---------------------------------------------------------------------------
__device__ __forceinline__ void scan_hist(const u32* h, u32 target,
                                          u32* binT_out, u32* c1_out) {
    const int lane = threadIdx.x & 63;
    const u32* hl = h + lane * 128;
    u32 partial = 0;
    for (int k = 0; k < 128; ++k) partial += hl[(k + lane) & 127];
    u32 v = partial;
#pragma unroll
    for (int off = 1; off < 64; off <<= 1) {
        u32 o = __shfl_down(v, off);
        if (lane + off < 64) v += o;
    }
    u32 above = v - partial;                 // bins in strictly-higher lanes
    if (above < target && above + partial >= target) {
        u32 cum = above;
        int bin = lane * 128 + 127;
        for (;; --bin) {
            cum += h[bin];
            if (cum >= target) break;
        }
        *binT_out = (u32)bin;
        if (c1_out) *c1_out = cum - h[bin];
    }
}

// ---------------------------------------------------------------------------
// Kernel 2: two-level histogram select -> compact (C<=1280) -> register-tiled
// enumeration rank (4 waves x 5 cands, rotating LDS reads) -> class-sparse
// mask NMS -> output. One 1024-thread block per batch.
// ---------------------------------------------------------------------------
__global__ __launch_bounds__(1024) void selnms_kernel(const float* __restrict__ pred,
                                                      const u64* __restrict__ keys,
                                                      float* __restrict__ out) {
    const int b    = blockIdx.x;
    const int tid  = threadIdx.x;
    const int wid  = tid >> 6;
    const int lane = tid & 63;

    alignas(16) __shared__ char SC[40960];         // phase-reused region
    __shared__ u64 keepm_s[16];
    __shared__ u32 binT_s, binT2_s, C1_s, cnt_s;
    __shared__ u32 cls_cnt[104], cls_start[104], cls_fill[104];

    u32* hist = (u32*)SC;                          // phase A/B: 8192 bins, 32 KB
    u64* cand = (u64*)SC;                          // phase C: 1280 keys @0 (10 KB)
    u64* sel  = (u64*)(SC + 10240);                // phase C/D: 1024 keys (8 KB)
    float* sx1 = (float*)(SC + 18432);             // phase D (NMS): 5*4 KB
    float* sy1 = (float*)(SC + 22528);
    float* sx2 = (float*)(SC + 26624);
    float* sy2 = (float*)(SC + 30720);
    float* sar = (float*)(SC + 34816);
    unsigned short* items = (unsigned short*)(SC + 38912);  // 2 KB

    const u64* K = keys + (size_t)b * N_DIM;

    if (tid < 100) { cls_cnt[tid] = 0u; cls_fill[tid] = 0u; }
    if (tid == 0) cnt_s = 0u;
    for (int i = tid; i < 8192; i += 1024) hist[i] = 0u;
    __syncthreads();

    // ---- level-1 histogram (LDS atomics; hot-bin serialization is cheap) ----
    for (int n = tid * 2; n < N_DIM; n += 2048) {
        ulonglong2 k2 = *reinterpret_cast<const ulonglong2*>(K + n);
        atomicAdd(&hist[key_bin1(k2.x)], 1u);
        atomicAdd(&hist[key_bin1(k2.y)], 1u);
    }
    __syncthreads();
    if (wid == 0) scan_hist(hist, TOPK_K, &binT_s, &C1_s);
    __syncthreads();
    const u32 binT = binT_s;
    const u32 C1   = C1_s;
    __syncthreads();

    // ---- level-2 histogram (keys in binT only) ----
    for (int i = tid; i < 8192; i += 1024) hist[i] = 0u;
    __syncthreads();
    for (int n = tid * 2; n < N_DIM; n += 2048) {
        ulonglong2 k2 = *reinterpret_cast<const ulonglong2*>(K + n);
        if (key_bin1(k2.x) == binT) atomicAdd(&hist[key_bin2(k2.x)], 1u);
        if (key_bin1(k2.y) == binT) atomicAdd(&hist[key_bin2(k2.y)], 1u);
    }
    __syncthreads();
    if (wid == 0) scan_hist(hist, TOPK_K - C1, &binT2_s, nullptr);
    __syncthreads();
    const u32 binT2 = binT2_s;
    __syncthreads();                               // hist dead -> cand region

    // ---- compact: (b1 > binT) || (b1 == binT && b2 >= binT2); C ~= 1030 ----
    for (int n = tid * 2; n < N_DIM; n += 2048) {
        ulonglong2 k2 = *reinterpret_cast<const ulonglong2*>(K + n);
        u32 b1x = key_bin1(k2.x);
        if (b1x > binT || (b1x == binT && key_bin2(k2.x) >= binT2)) {
            u32 p = atomicAdd(&cnt_s, 1u);
            if (p < CAND_CAP) cand[p] = k2.x;
        }
        u32 b1y = key_bin1(k2.y);
        if (b1y > binT || (b1y == binT && key_bin2(k2.y) >= binT2)) {
            u32 p = atomicAdd(&cnt_s, 1u);
            if (p < CAND_CAP) cand[p] = k2.y;
        }
    }
    __syncthreads();
    int C = (int)cnt_s; if (C > CAND_CAP) C = CAND_CAP;
    for (int i = C + tid; i < CAND_CAP; i += 1024) cand[i] = 0ull;  // pad
    __syncthreads();

    // ---- enumeration rank: 4 waves (SIMD-spread), 5 cands/thread in regs,
    //      rotating per-lane ulonglong2 reads (each wave ingests cand once) ----
    if (tid < 256) {
        u64 my0 = cand[tid * 5 + 0];
        u64 my1 = cand[tid * 5 + 1];
        u64 my2 = cand[tid * 5 + 2];
        u64 my3 = cand[tid * 5 + 3];
        u64 my4 = cand[tid * 5 + 4];
        u32 c0 = 0, c1 = 0, c2n = 0, c3 = 0, c4 = 0;
        const ulonglong2* cp = (const ulonglong2*)cand;
        int j = tid;                                   // < 640
        for (int i = 0; i < CAND_CAP / 2; ++i) {
            ulonglong2 p = cp[j];
            ++j; if (j == CAND_CAP / 2) j = 0;
            c0  += (p.x > my0) + (p.y > my0);
            c1  += (p.x > my1) + (p.y > my1);
            c2n += (p.x > my2) + (p.y > my2);
            c3  += (p.x > my3) + (p.y > my3);
            c4  += (p.x > my4) + (p.y > my4);
        }
        // unique keys -> unique ranks; pads (0) rank >= C >= 1024, never written
        if (c0  < TOPK_K) sel[c0]  = my0;
        if (c1  < TOPK_K) sel[c1]  = my1;
        if (c2n < TOPK_K) sel[c2n] = my2;
        if (c3  < TOPK_K) sel[c3]  = my3;
        if (c4  < TOPK_K) sel[c4]  = my4;
    }
    __syncthreads();

    // ---- decode rank-tid box ----
    u64 key = sel[tid];
    int lab = (int)(key & 0x7Full);
    int n   = (N_DIM - 1) - (int)((key >> 7) & (u64)(N_DIM - 1));
    u32 ou  = (u32)(key >> 22);
    u32 ob  = (ou & 0x80000000u) ? (ou & 0x7FFFFFFFu) : ~ou;
    float score = __uint_as_float(ob);
    bool validk = (score >= 0.0f);

    const float* row = pred + ((size_t)b * N_DIM + n) * ROW_F;
    float cx = row[0], cy = row[1], w = row[2], h = row[3];
    float x1 = cx - w * 0.5f, y1 = cy - h * 0.5f;
    float x2 = w + x1,        y2 = h + y1;         // reference: xy2 = wh + xy1
    float off = (float)lab * OFFSET_F;
    float nx1 = x1 + off, ny1 = y1 + off, nx2 = x2 + off, ny2 = y2 + off;
    float area = (nx2 - nx1) * (ny2 - ny1);

    sx1[tid] = nx1; sy1[tid] = ny1; sx2[tid] = nx2; sy2[tid] = ny2; sar[tid] = area;
    atomicAdd(&cls_cnt[lab], 1u);
    __syncthreads();
    if (tid == 0) {
        u32 s = 0;
        for (int c = 0; c < 100; ++c) { cls_start[c] = s; s += cls_cnt[c]; }
    }
    __syncthreads();
    {
        u32 p = cls_start[lab] + atomicAdd(&cls_fill[lab], 1u);
        items[p] = (unsigned short)tid;
    }
    __syncthreads();

    // ---- suppression-mask column, same-class partners only (~10 IoUs) ----
    // Cross-class IoU is exactly 0 (class offset 241 >= extent bound 231).
    u64 m0=0,m1=0,m2=0,m3=0,m4=0,m5=0,m6=0,m7=0,
        m8=0,m9=0,m10=0,m11=0,m12=0,m13=0,m14=0,m15=0;
    {
        const int s0 = (int)cls_start[lab];
        const int e0 = s0 + (int)cls_cnt[lab];
        for (int p = s0; p < e0; ++p) {
            int i = (int)items[p];
            if (i == tid) continue;
            float ix1 = fmaxf(sx1[i], nx1), iy1 = fmaxf(sy1[i], ny1);
            float ix2 = fminf(sx2[i], nx2), iy2 = fminf(sy2[i], ny2);
            float iw = fmaxf(ix2 - ix1, 0.0f), ih = fmaxf(iy2 - iy1, 0.0f);
            float inter = iw * ih;
            float iou = inter / (sar[i] + area - inter + 1e-12f);
            if (iou > NMS_THRE_F) {
                u64 bit = 1ull << (i & 63);
                int ch = i >> 6;
                m0  |= (ch == 0)  ? bit : 0ull;  m1  |= (ch == 1)  ? bit : 0ull;
                m2  |= (ch == 2)  ? bit : 0ull;  m3  |= (ch == 3)  ? bit : 0ull;
                m4  |= (ch == 4)  ? bit : 0ull;  m5  |= (ch == 5)  ? bit : 0ull;
                m6  |= (ch == 6)  ? bit : 0ull;  m7  |= (ch == 7)  ? bit : 0ull;
                m8  |= (ch == 8)  ? bit : 0ull;  m9  |= (ch == 9)  ? bit : 0ull;
                m10 |= (ch == 10) ? bit : 0ull;  m11 |= (ch == 11) ? bit : 0ull;
                m12 |= (ch == 12) ? bit : 0ull;  m13 |= (ch == 13) ? bit : 0ull;
                m14 |= (ch == 14) ? bit : 0ull;  m15 |= (ch == 15) ? bit : 0ull;
            }
        }
    }

    // ---- greedy scan, 16 chunks; serial work only on conflicted lanes ----
    bool supp = false, keepb = false;
#define CHUNK_STEP(c, mc)                                                     \
    {                                                                         \
        if (wid == (c)) {                                                     \
            u64 W  = (mc);                                                    \
            u64 vm = __ballot(validk && !supp);                               \
            u64 S  = __ballot(W != 0ull);                                     \
            u64 km = vm & ~S;                                                 \
            u64 suppm = 0ull, mm = S;                                         \
            while (mm) {                                                      \
                int i = __builtin_ctzll(mm); mm &= mm - 1ull;                 \
                u64 Wi = shfl64(W, i);                                        \
                if (((vm >> i) & 1ull) && !((suppm >> i) & 1ull)) {           \
                    km |= 1ull << i; suppm |= Wi;                             \
                }                                                             \
            }                                                                 \
            keepb = ((km >> lane) & 1ull) != 0ull;                            \
            if (lane == 0) keepm_s[(c)] = km;                                 \
        }                                                                     \
        __syncthreads();                                                      \
        if (wid > (c) && ((mc) & keepm_s[(c)])) supp = true;                  \
    }
    CHUNK_STEP(0, m0)   CHUNK_STEP(1, m1)   CHUNK_STEP(2, m2)   CHUNK_STEP(3, m3)
    CHUNK_STEP(4, m4)   CHUNK_STEP(5, m5)   CHUNK_STEP(6, m6)   CHUNK_STEP(7, m7)
    CHUNK_STEP(8, m8)   CHUNK_STEP(9, m9)   CHUNK_STEP(10, m10) CHUNK_STEP(11, m11)
    CHUNK_STEP(12, m12) CHUNK_STEP(13, m13) CHUNK_STEP(14, m14) CHUNK_STEP(15, m15)
#undef CHUNK_STEP

    float keepf = keepb ? 1.0f : 0.0f;
    float2* o2 = (float2*)(out + ((size_t)b * TOPK_K + tid) * 6);
    o2[0] = make_float2(x1 * keepf, y1 * keepf);
    o2[1] = make_float2(x2 * keepf, y2 * keepf);
    o2[2] = make_float2(score * keepf, (float)lab * keepf);
}

// ---------------------------------------------------------------------------
extern "C" void kernel_launch(void* const* d_in, const int* in_sizes, int n_in,
                              void* d_out, int out_size, void* d_ws, size_t ws_size,
                              hipStream_t stream) {
    const float* pred = (const float*)d_in[0];
    float* out = (float*)d_out;

    u64* keys = (u64*)d_ws;   // 2 MB

    decode_kernel<<<(B_DIM * N_DIM) / 256, 256, 0, stream>>>(pred, keys);
    selnms_kernel<<<B_DIM, 1024, 0, stream>>>(pred, keys, out);
}

// Round 6
// 65.265 us; speedup vs baseline: 6.5425x; 1.5930x over previous
//
#include <hip/hip_runtime.h>
#include <hip/hip_bf16.h>

// Keep every fp op matching numpy/jax f32 op-by-op rounding (no fma fusion):
#pragma clang fp contract(off)

#define NUM_CLASSES 100
#define B_DIM 8
#define N_DIM 32768
#define TOPK_K 1024
#define ROW_F 105
#define CONF_THRE_F 0.001f
#define NMS_THRE_F 0.65f
#define OFFSET_F 241.0f   // MAX_DIM + 1
#define T0_F 0.95f        // prefilter threshold (fast path iff 1024<=cnt<=2048)
#define CAND_CAP 2048

typedef unsigned long long u64;
typedef unsigned int u32;

__device__ __forceinline__ u64 shfl64(u64 v, int src) {
    int lo = __shfl((int)(v & 0xFFFFFFFFull), src);
    int hi = __shfl((int)(v >> 32), src);
    return ((u64)(u32)hi << 32) | (u32)lo;
}
__device__ __forceinline__ u64 shfl_xor64(u64 v, int mask) {
    int lo = __shfl_xor((int)(v & 0xFFFFFFFFull), mask);
    int hi = __shfl_xor((int)(v >> 32), mask);
    return ((u64)(u32)hi << 32) | (u32)lo;
}

// key layout (54 bits): [ou(32) << 22] | [(32767-n)(15) << 7] | class(7)
__device__ __forceinline__ u32 key_bin1(u64 k) {   // ou bits 30..18, 0 if invalid
    return ((k >> 53) & 1ull) ? (u32)((k >> 40) & 0x1FFFull) : 0u;
}
__device__ __forceinline__ u32 key_bin2(u64 k) {   // ou bits 17..5
    return (u32)((k >> 27) & 0x1FFFull);
}

// ---------------------------------------------------------------------------
// Kernel 1: decode. Double-buffered LDS staging (prefetch chunk c+1 while
// wave 0 scans chunk c). Wave-ballot append of prefiltered candidates
// (key + raw box) to per-batch global lists.
// ---------------------------------------------------------------------------
__global__ __launch_bounds__(256) void decode_kernel(const float* __restrict__ pred,
                                                     u64* __restrict__ keys,
                                                     u64* __restrict__ cand,
                                                     float4* __restrict__ cbox,
                                                     u32* __restrict__ cnt) {
    __shared__ float buf[2][64 * ROW_F];         // 2 x 26880 B
    const int tid = threadIdx.x;
    const int rb  = blockIdx.x << 8;             // 256 rows per block
    const int bat = rb >> 15;                    // batch (128 blocks/batch)

    {   // preload chunk 0
        const float4* src = reinterpret_cast<const float4*>(pred + (size_t)rb * ROW_F);
        float4* dst = reinterpret_cast<float4*>(buf[0]);
#pragma unroll
        for (int i = 0; i < 7; ++i) {
            int idx = tid + (i << 8);
            if (idx < 1680) dst[idx] = src[idx];
        }
    }
    __syncthreads();

    for (int c = 0; c < 4; ++c) {
        if (c < 3) {   // prefetch next chunk (overlaps wave-0 scan below)
            const float4* src = reinterpret_cast<const float4*>(
                pred + (size_t)(rb + ((c + 1) << 6)) * ROW_F);
            float4* dst = reinterpret_cast<float4*>(buf[(c + 1) & 1]);
#pragma unroll
            for (int i = 0; i < 7; ++i) {
                int idx = tid + (i << 8);
                if (idx < 1680) dst[idx] = src[idx];
            }
        }
        if (tid < 64) {   // wave 0 scans chunk c
            const float* R = buf[c & 1] + tid * ROW_F;
            float obj = R[4];
            u32 bb = 0u; int cls = 0;
#pragma unroll 10
            for (int k = 5; k < 105; ++k) {
                // class scores >= 0: bit order == float order; strict '>' with
                // k ascending keeps the FIRST max (== jnp.argmax).
                u32 bf = __float_as_uint(R[k]) | 0x80000000u;
                if (bf > bb) { bb = bf; cls = k - 5; }
            }
            float cmax = __uint_as_float(bb & 0x7FFFFFFFu);
            float score = obj * cmax;                    // reference op order
            bool valid = (score * cmax) >= CONF_THRE_F;
            float mval = valid ? score : -1.0f;
            u32 u  = __float_as_uint(mval);
            u32 ou = (u & 0x80000000u) ? ~u : (u | 0x80000000u);
            int r = rb + (c << 6) + tid;
            u64 key = ((u64)ou << 22) |
                      ((u64)(u32)((r & (N_DIM - 1)) ^ (N_DIM - 1)) << 7) |
                      (u64)cls;
            keys[r] = key;

            // prefilter append (wave-aggregated: one global atomic per wave)
            bool want = (mval >= T0_F);
            u64 mk = __ballot(want);
            u32 base = 0;
            if (tid == 0 && mk) base = atomicAdd(&cnt[bat << 5], (u32)__popcll(mk));
            base = (u32)__shfl((int)base, 0);
            if (want) {
                u32 pos = base + (u32)__popcll(mk & ((1ull << tid) - 1ull));
                if (pos < CAND_CAP) {
                    cand[(bat << 11) + pos] = key;
                    cbox[(bat << 11) + pos] = make_float4(R[0], R[1], R[2], R[3]);
                }
            }
        }
        __syncthreads();
    }
}

// ---------------------------------------------------------------------------
// wave-0 suffix scan over 8192-bin LDS hist (rotated reads: conflict-free).
// FALLBACK path only.
// ---------------------------------------------------------------------------
__device__ __forceinline__ void scan_hist(const u32* h, u32 target,
                                          u32* binT_out, u32* c1_out) {
    const int lane = threadIdx.x & 63;
    const u32* hl = h + lane * 128;
    u32 partial = 0;
    for (int k = 0; k < 128; ++k) partial += hl[(k + lane) & 127];
    u32 v = partial;
#pragma unroll
    for (int off = 1; off < 64; off <<= 1) {
        u32 o = __shfl_down(v, off);
        if (lane + off < 64) v += o;
    }
    u32 above = v - partial;
    if (above < target && above + partial >= target) {
        u32 cum = above;
        int bin = lane * 128 + 127;
        for (;; --bin) {
            cum += h[bin];
            if (cum >= target) break;
        }
        *binT_out = (u32)bin;
        if (c1_out) *c1_out = cum - h[bin];
    }
}

// ---------------------------------------------------------------------------
// Kernel 2: candidates (prefiltered fast path, or histogram-select fallback)
// -> exact bucket rank (256 buckets over top varying key bits) -> class-sparse
// mask NMS -> output. One 1024-thread block per batch.
// ---------------------------------------------------------------------------
__global__ __launch_bounds__(1024) void selnms_kernel(const float* __restrict__ pred,
                                                      const u64* __restrict__ keys,
                                                      const u64* __restrict__ cand_g,
                                                      const float4* __restrict__ cbox_g,
                                                      const u32* __restrict__ cnt_g,
                                                      float* __restrict__ out) {
    const int b    = blockIdx.x;
    const int tid  = threadIdx.x;
    const int wid  = tid >> 6;
    const int lane = tid & 63;

    __shared__ u64 sel[TOPK_K];                    // 8 KB
    alignas(16) __shared__ char SC[49152];         // 48 KB phase-reused
    __shared__ u64 keepm_s[16];
    __shared__ u64 wmin_s[16], wmax_s[16];
    __shared__ u64 kmin_s;
    __shared__ u32 shift_s;
    __shared__ u32 bcnt[256], bfill[256], bstart[257];
    __shared__ u32 cls_cnt[100], cls_start[100], cls_fill[100];
    __shared__ u32 binT_s, binT2_s, C1_s, cntS_s;

    u64* candS    = (u64*)SC;                      // [0,16K)
    u64* bucketed = (u64*)(SC + 16384);            // [16K,32K)
    u32* hist     = (u32*)(SC + 16384);            // [16K,48K) fallback only
    float* sx1 = (float*)SC;                       // [0,4K)   (after rank)
    float* sy1 = (float*)(SC + 4096);
    float* sx2 = (float*)(SC + 8192);
    float* sy2 = (float*)(SC + 12288);
    float* sar = (float*)(SC + 16384);             // [16K,20K) (after rank+bar)
    unsigned short* items = (unsigned short*)(SC + 20480);  // [20K,22K)
    float4* rbox = (float4*)(SC + 32768);          // [32K,48K)

    if (tid < 256) { bcnt[tid] = 0u; bfill[tid] = 0u; }
    if (tid < 100) { cls_cnt[tid] = 0u; cls_fill[tid] = 0u; }
    if (tid == 0) cntS_s = 0u;

    const u32 cnt = cnt_g[b << 5];
    const bool fast = (cnt >= TOPK_K && cnt <= CAND_CAP);
    int C;

    if (fast) {
        C = (int)cnt;
        for (int i = tid; i < C; i += 1024) candS[i] = cand_g[(b << 11) + i];
        __syncthreads();
    } else {
        // ---------------- FALLBACK: r5 two-level histogram select ----------
        const u64* K = keys + (size_t)b * N_DIM;
        for (int i = tid; i < 8192; i += 1024) hist[i] = 0u;
        __syncthreads();
        for (int n = tid * 2; n < N_DIM; n += 2048) {
            ulonglong2 k2 = *reinterpret_cast<const ulonglong2*>(K + n);
            atomicAdd(&hist[key_bin1(k2.x)], 1u);
            atomicAdd(&hist[key_bin1(k2.y)], 1u);
        }
        __syncthreads();
        if (wid == 0) scan_hist(hist, TOPK_K, &binT_s, &C1_s);
        __syncthreads();
        const u32 binT = binT_s;
        const u32 C1   = C1_s;
        __syncthreads();
        for (int i = tid; i < 8192; i += 1024) hist[i] = 0u;
        __syncthreads();
        for (int n = tid * 2; n < N_DIM; n += 2048) {
            ulonglong2 k2 = *reinterpret_cast<const ulonglong2*>(K + n);
            if (key_bin1(k2.x) == binT) atomicAdd(&hist[key_bin2(k2.x)], 1u);
            if (key_bin1(k2.y) == binT) atomicAdd(&hist[key_bin2(k2.y)], 1u);
        }
        __syncthreads();
        if (wid == 0) scan_hist(hist, TOPK_K - C1, &binT2_s, nullptr);
        __syncthreads();
        const u32 binT2 = binT2_s;
        __syncthreads();                           // hist dead
        for (int n = tid * 2; n < N_DIM; n += 2048) {
            ulonglong2 k2 = *reinterpret_cast<const ulonglong2*>(K + n);
            u32 b1x = key_bin1(k2.x);
            if (b1x > binT || (b1x == binT && key_bin2(k2.x) >= binT2)) {
                u32 p = atomicAdd(&cntS_s, 1u);
                if (p < CAND_CAP) candS[p] = k2.x;
            }
            u32 b1y = key_bin1(k2.y);
            if (b1y > binT || (b1y == binT && key_bin2(k2.y) >= binT2)) {
                u32 p = atomicAdd(&cntS_s, 1u);
                if (p < CAND_CAP) candS[p] = k2.y;
            }
        }
        __syncthreads();
        C = (int)cntS_s; if (C > CAND_CAP) C = CAND_CAP;
    }

    // ---- min/max over candidate keys ----
    u64 kmn = ~0ull, kmx = 0ull;
    for (int i = tid; i < C; i += 1024) {
        u64 k = candS[i];
        if (k < kmn) kmn = k;
        if (k > kmx) kmx = k;
    }
#pragma unroll
    for (int off = 32; off; off >>= 1) {
        u64 a = shfl_xor64(kmn, off); if (a < kmn) kmn = a;
        u64 m = shfl_xor64(kmx, off); if (m > kmx) kmx = m;
    }
    if (lane == 0) { wmin_s[wid] = kmn; wmax_s[wid] = kmx; }
    __syncthreads();
    if (tid == 0) {
        u64 mn = wmin_s[0], mx = wmax_s[0];
        for (int i = 1; i < 16; ++i) {
            if (wmin_s[i] < mn) mn = wmin_s[i];
            if (wmax_s[i] > mx) mx = wmax_s[i];
        }
        kmin_s = mn;
        u64 d = mx - mn;
        int pos = 63 - __clzll(d | 1ull);
        shift_s = (pos > 7) ? (u32)(pos - 7) : 0u;
    }
    __syncthreads();
    const u64 kmin = kmin_s;
    const u32 shift = shift_s;

    // ---- bucket histogram (exact, monotonic bucketing) ----
    const bool own0 = (tid < C);
    const bool own1 = (tid + 1024 < C);
    u64 key0 = 0, key1 = 0; u32 bkt0 = 0, bkt1 = 0;
    if (own0) { key0 = candS[tid];        bkt0 = (u32)((key0 - kmin) >> shift); atomicAdd(&bcnt[bkt0], 1u); }
    if (own1) { key1 = candS[tid + 1024]; bkt1 = (u32)((key1 - kmin) >> shift); atomicAdd(&bcnt[bkt1], 1u); }
    __syncthreads();
    if (wid == 0) {   // exclusive prefix over 256 bins
        u32 s0 = bcnt[lane * 4], s1 = bcnt[lane * 4 + 1],
            s2 = bcnt[lane * 4 + 2], s3 = bcnt[lane * 4 + 3];
        u32 tot = s0 + s1 + s2 + s3;
        u32 incl = tot;
#pragma unroll
        for (int off = 1; off < 64; off <<= 1) {
            u32 v = (u32)__shfl_up((int)incl, off);
            if (lane >= off) incl += v;
        }
        u32 ex = incl - tot;
        bstart[lane * 4]     = ex;
        bstart[lane * 4 + 1] = ex + s0;
        bstart[lane * 4 + 2] = ex + s0 + s1;
        bstart[lane * 4 + 3] = ex + s0 + s1 + s2;
        if (lane == 63) bstart[256] = incl;
    }
    __syncthreads();
    if (own0) { u32 p = bstart[bkt0] + atomicAdd(&bfill[bkt0], 1u); bucketed[p] = key0; }
    if (own1) { u32 p = bstart[bkt1] + atomicAdd(&bfill[bkt1], 1u); bucketed[p] = key1; }
    __syncthreads();

    // ---- exact rank within bucket + write rank-ordered NMS inputs ----
    u32 rank0 = ~0u, rank1 = ~0u; float area0 = 0.f, area1 = 0.f;
#define RANK_ONE(own, mykey, mybkt, slot, rankv, areav)                       \
    if (own) {                                                                \
        u32 lo = bstart[mybkt], hi = bstart[mybkt + 1];                       \
        u32 g = 0;                                                            \
        for (u32 p = lo; p < hi; ++p) g += (bucketed[p] > (mykey));           \
        u32 rk = ((u32)C - hi) + g;                                           \
        if (rk < TOPK_K) {                                                    \
            rankv = rk;                                                       \
            float4 bx;                                                        \
            if (fast) bx = cbox_g[(b << 11) + (slot)];                        \
            else {                                                            \
                int n = (N_DIM - 1) - (int)(((mykey) >> 7) & (u64)(N_DIM - 1)); \
                const float* row = pred + ((size_t)b * N_DIM + n) * ROW_F;    \
                bx = make_float4(row[0], row[1], row[2], row[3]);             \
            }                                                                 \
            int lab = (int)((mykey) & 0x7Full);                               \
            float x1 = bx.x - bx.z * 0.5f, y1 = bx.y - bx.w * 0.5f;           \
            float x2 = bx.z + x1,          y2 = bx.w + y1;                    \
            float off = (float)lab * OFFSET_F;                                \
            float nx1 = x1 + off, ny1 = y1 + off;                             \
            float nx2 = x2 + off, ny2 = y2 + off;                             \
            areav = (nx2 - nx1) * (ny2 - ny1);                                \
            sel[rk] = (mykey);                                                \
            sx1[rk] = nx1; sy1[rk] = ny1; sx2[rk] = nx2; sy2[rk] = ny2;       \
            rbox[rk] = make_float4(x1, y1, x2, y2);                           \
        }                                                                     \
    }
    RANK_ONE(own0, key0, bkt0, tid,        rank0, area0)
    RANK_ONE(own1, key1, bkt1, tid + 1024, rank1, area1)
#undef RANK_ONE
    __syncthreads();                               // bucketed dead
    if (rank0 != ~0u) sar[rank0] = area0;
    if (rank1 != ~0u) sar[rank1] = area1;

    // ---- per-rank decode + class lists ----
    u64 key = sel[tid];
    int lab = (int)(key & 0x7Full);
    u32 ou  = (u32)(key >> 22);
    u32 ob  = (ou & 0x80000000u) ? (ou & 0x7FFFFFFFu) : ~ou;
    float score = __uint_as_float(ob);
    bool validk = (score >= 0.0f);
    atomicAdd(&cls_cnt[lab], 1u);
    __syncthreads();
    if (wid == 0) {   // exclusive prefix over 100 class bins
        u32 s0 = (lane < 50) ? cls_cnt[lane * 2] : 0u;
        u32 s1 = (lane < 50) ? cls_cnt[lane * 2 + 1] : 0u;
        u32 tot = s0 + s1;
        u32 incl = tot;
#pragma unroll
        for (int off = 1; off < 64; off <<= 1) {
            u32 v = (u32)__shfl_up((int)incl, off);
            if (lane >= off) incl += v;
        }
        u32 ex = incl - tot;
        if (lane < 50) { cls_start[lane * 2] = ex; cls_start[lane * 2 + 1] = ex + s0; }
    }
    __syncthreads();
    {
        u32 p = cls_start[lab] + atomicAdd(&cls_fill[lab], 1u);
        items[p] = (unsigned short)tid;
    }
    __syncthreads();

    const float nx1 = sx1[tid], ny1 = sy1[tid], nx2 = sx2[tid], ny2 = sy2[tid];
    const float area = sar[tid];

    // ---- suppression-mask column, same-class partners only (~10 IoUs) ----
    // Cross-class IoU is exactly 0 (class offset 241 >= extent bound 231).
    u64 m0=0,m1=0,m2=0,m3=0,m4=0,m5=0,m6=0,m7=0,
        m8=0,m9=0,m10=0,m11=0,m12=0,m13=0,m14=0,m15=0;
    {
        const int s0 = (int)cls_start[lab];
        const int e0 = s0 + (int)cls_cnt[lab];
        for (int p = s0; p < e0; ++p) {
            int i = (int)items[p];
            if (i == tid) continue;
            float ix1 = fmaxf(sx1[i], nx1), iy1 = fmaxf(sy1[i], ny1);
            float ix2 = fminf(sx2[i], nx2), iy2 = fminf(sy2[i], ny2);
            float iw = fmaxf(ix2 - ix1, 0.0f), ih = fmaxf(iy2 - iy1, 0.0f);
            float inter = iw * ih;
            float iou = inter / (sar[i] + area - inter + 1e-12f);
            if (iou > NMS_THRE_F) {
                u64 bit = 1ull << (i & 63);
                int ch = i >> 6;
                m0  |= (ch == 0)  ? bit : 0ull;  m1  |= (ch == 1)  ? bit : 0ull;
                m2  |= (ch == 2)  ? bit : 0ull;  m3  |= (ch == 3)  ? bit : 0ull;
                m4  |= (ch == 4)  ? bit : 0ull;  m5  |= (ch == 5)  ? bit : 0ull;
                m6  |= (ch == 6)  ? bit : 0ull;  m7  |= (ch == 7)  ? bit : 0ull;
                m8  |= (ch == 8)  ? bit : 0ull;  m9  |= (ch == 9)  ? bit : 0ull;
                m10 |= (ch == 10) ? bit : 0ull;  m11 |= (ch == 11) ? bit : 0ull;
                m12 |= (ch == 12) ? bit : 0ull;  m13 |= (ch == 13) ? bit : 0ull;
                m14 |= (ch == 14) ? bit : 0ull;  m15 |= (ch == 15) ? bit : 0ull;
            }
        }
    }

    // ---- greedy scan, 16 chunks; serial work only on conflicted lanes ----
    bool supp = false, keepb = false;
#define CHUNK_STEP(c, mc)                                                     \
    {                                                                         \
        if (wid == (c)) {                                                     \
            u64 W  = (mc);                                                    \
            u64 vm = __ballot(validk && !supp);                               \
            u64 S  = __ballot(W != 0ull);                                     \
            u64 km = vm & ~S;                                                 \
            u64 suppm = 0ull, mm = S;                                         \
            while (mm) {                                                      \
                int i = __builtin_ctzll(mm); mm &= mm - 1ull;                 \
                u64 Wi = shfl64(W, i);                                        \
                if (((vm >> i) & 1ull) && !((suppm >> i) & 1ull)) {           \
                    km |= 1ull << i; suppm |= Wi;                             \
                }                                                             \
            }                                                                 \
            keepb = ((km >> lane) & 1ull) != 0ull;                            \
            if (lane == 0) keepm_s[(c)] = km;                                 \
        }                                                                     \
        __syncthreads();                                                      \
        if (wid > (c) && ((mc) & keepm_s[(c)])) supp = true;                  \
    }
    CHUNK_STEP(0, m0)   CHUNK_STEP(1, m1)   CHUNK_STEP(2, m2)   CHUNK_STEP(3, m3)
    CHUNK_STEP(4, m4)   CHUNK_STEP(5, m5)   CHUNK_STEP(6, m6)   CHUNK_STEP(7, m7)
    CHUNK_STEP(8, m8)   CHUNK_STEP(9, m9)   CHUNK_STEP(10, m10) CHUNK_STEP(11, m11)
    CHUNK_STEP(12, m12) CHUNK_STEP(13, m13) CHUNK_STEP(14, m14) CHUNK_STEP(15, m15)
#undef CHUNK_STEP

    float keepf = keepb ? 1.0f : 0.0f;
    float4 rb4 = rbox[tid];
    float2* o2 = (float2*)(out + ((size_t)b * TOPK_K + tid) * 6);
    o2[0] = make_float2(rb4.x * keepf, rb4.y * keepf);
    o2[1] = make_float2(rb4.z * keepf, rb4.w * keepf);
    o2[2] = make_float2(score * keepf, (float)lab * keepf);
}

// ---------------------------------------------------------------------------
extern "C" void kernel_launch(void* const* d_in, const int* in_sizes, int n_in,
                              void* d_out, int out_size, void* d_ws, size_t ws_size,
                              hipStream_t stream) {
    const float* pred = (const float*)d_in[0];
    float* out = (float*)d_out;

    // workspace layout
    u64*    keys = (u64*)d_ws;                                       // 2 MB
    u64*    cand = (u64*)((char*)d_ws + (2u << 20));                 // 128 KB
    float4* cbox = (float4*)((char*)d_ws + (2u << 20) + (128u << 10)); // 256 KB
    u32*    cnt  = (u32*)((char*)d_ws + (2u << 20) + (384u << 10));  // 1 KB

    hipMemsetAsync(cnt, 0, B_DIM * 32 * sizeof(u32), stream);
    decode_kernel<<<(B_DIM * N_DIM) / 256, 256, 0, stream>>>(pred, keys, cand, cbox, cnt);
    selnms_kernel<<<B_DIM, 1024, 0, stream>>>(pred, keys, cand, cbox, cnt, out);
}

// Round 7
// 64.582 us; speedup vs baseline: 6.6116x; 1.0106x over previous
//
#include <hip/hip_runtime.h>
#include <hip/hip_bf16.h>

// Keep every fp op matching numpy/jax f32 op-by-op rounding (no fma fusion):
#pragma clang fp contract(off)

#define NUM_CLASSES 100
#define B_DIM 8
#define N_DIM 32768
#define TOPK_K 1024
#define ROW_F 105
#define CONF_THRE_F 0.001f
#define NMS_THRE_F 0.65f
#define OFFSET_F 241.0f   // MAX_DIM + 1
#define T0_F 0.95f        // prefilter threshold (fast path iff 1024<=cnt<=2048)
#define CAND_CAP 2048

typedef unsigned long long u64;
typedef unsigned int u32;

__device__ __forceinline__ u64 shfl64(u64 v, int src) {
    int lo = __shfl((int)(v & 0xFFFFFFFFull), src);
    int hi = __shfl((int)(v >> 32), src);
    return ((u64)(u32)hi << 32) | (u32)lo;
}
__device__ __forceinline__ u64 shfl_xor64(u64 v, int mask) {
    int lo = __shfl_xor((int)(v & 0xFFFFFFFFull), mask);
    int hi = __shfl_xor((int)(v >> 32), mask);
    return ((u64)(u32)hi << 32) | (u32)lo;
}

// key layout (54 bits): [ou(32) << 22] | [(32767-n)(15) << 7] | class(7)
__device__ __forceinline__ u32 key_bin1(u64 k) {   // ou bits 30..18, 0 if invalid
    return ((k >> 53) & 1ull) ? (u32)((k >> 40) & 0x1FFFull) : 0u;
}
__device__ __forceinline__ u32 key_bin2(u64 k) {   // ou bits 17..5
    return (u32)((k >> 27) & 0x1FFFull);
}

// ---------------------------------------------------------------------------
// Kernel 1: decode. Double-buffered LDS staging (prefetch chunk c+1 while
// wave 0 scans chunk c). Wave-ballot append of prefiltered candidates
// (key + raw box) to per-batch global lists.
// ---------------------------------------------------------------------------
__global__ __launch_bounds__(256) void decode_kernel(const float* __restrict__ pred,
                                                     u64* __restrict__ keys,
                                                     u64* __restrict__ cand,
                                                     float4* __restrict__ cbox,
                                                     u32* __restrict__ cnt) {
    __shared__ float buf[2][64 * ROW_F];         // 2 x 26880 B
    const int tid = threadIdx.x;
    const int rb  = blockIdx.x << 8;             // 256 rows per block
    const int bat = rb >> 15;                    // batch (128 blocks/batch)

    {   // preload chunk 0
        const float4* src = reinterpret_cast<const float4*>(pred + (size_t)rb * ROW_F);
        float4* dst = reinterpret_cast<float4*>(buf[0]);
#pragma unroll
        for (int i = 0; i < 7; ++i) {
            int idx = tid + (i << 8);
            if (idx < 1680) dst[idx] = src[idx];
        }
    }
    __syncthreads();

    for (int c = 0; c < 4; ++c) {
        if (c < 3) {   // prefetch next chunk (overlaps wave-0 scan below)
            const float4* src = reinterpret_cast<const float4*>(
                pred + (size_t)(rb + ((c + 1) << 6)) * ROW_F);
            float4* dst = reinterpret_cast<float4*>(buf[(c + 1) & 1]);
#pragma unroll
            for (int i = 0; i < 7; ++i) {
                int idx = tid + (i << 8);
                if (idx < 1680) dst[idx] = src[idx];
            }
        }
        if (tid < 64) {   // wave 0 scans chunk c
            const float* R = buf[c & 1] + tid * ROW_F;
            float obj = R[4];
            u32 bb = 0u; int cls = 0;
#pragma unroll 10
            for (int k = 5; k < 105; ++k) {
                // class scores >= 0: bit order == float order; strict '>' with
                // k ascending keeps the FIRST max (== jnp.argmax).
                u32 bf = __float_as_uint(R[k]) | 0x80000000u;
                if (bf > bb) { bb = bf; cls = k - 5; }
            }
            float cmax = __uint_as_float(bb & 0x7FFFFFFFu);
            float score = obj * cmax;                    // reference op order
            bool valid = (score * cmax) >= CONF_THRE_F;
            float mval = valid ? score : -1.0f;
            u32 u  = __float_as_uint(mval);
            u32 ou = (u & 0x80000000u) ? ~u : (u | 0x80000000u);
            int r = rb + (c << 6) + tid;
            u64 key = ((u64)ou << 22) |
                      ((u64)(u32)((r & (N_DIM - 1)) ^ (N_DIM - 1)) << 7) |
                      (u64)cls;
            keys[r] = key;

            // prefilter append (wave-aggregated: one global atomic per wave)
            bool want = (mval >= T0_F);
            u64 mk = __ballot(want);
            u32 base = 0;
            if (tid == 0 && mk) base = atomicAdd(&cnt[bat << 5], (u32)__popcll(mk));
            base = (u32)__shfl((int)base, 0);
            if (want) {
                u32 pos = base + (u32)__popcll(mk & ((1ull << tid) - 1ull));
                if (pos < CAND_CAP) {
                    cand[(bat << 11) + pos] = key;
                    cbox[(bat << 11) + pos] = make_float4(R[0], R[1], R[2], R[3]);
                }
            }
        }
        __syncthreads();
    }
}

// ---------------------------------------------------------------------------
// wave-0 suffix scan over 8192-bin LDS hist (rotated reads: conflict-free).
// FALLBACK path only.
// ---------------------------------------------------------------------------
__device__ __forceinline__ void scan_hist(const u32* h, u32 target,
                                          u32* binT_out, u32* c1_out) {
    const int lane = threadIdx.x & 63;
    const u32* hl = h + lane * 128;
    u32 partial = 0;
    for (int k = 0; k < 128; ++k) partial += hl[(k + lane) & 127];
    u32 v = partial;
#pragma unroll
    for (int off = 1; off < 64; off <<= 1) {
        u32 o = __shfl_down(v, off);
        if (lane + off < 64) v += o;
    }
    u32 above = v - partial;
    if (above < target && above + partial >= target) {
        u32 cum = above;
        int bin = lane * 128 + 127;
        for (;; --bin) {
            cum += h[bin];
            if (cum >= target) break;
        }
        *binT_out = (u32)bin;
        if (c1_out) *c1_out = cum - h[bin];
    }
}

// ---------------------------------------------------------------------------
// Kernel 2: candidates (prefiltered fast path, or histogram-select fallback)
// -> exact bucket rank (256 buckets over top varying key bits) -> class-sparse
// mask NMS -> output. One 1024-thread block per batch.
// ---------------------------------------------------------------------------
__global__ __launch_bounds__(1024) void selnms_kernel(const float* __restrict__ pred,
                                                      const u64* __restrict__ keys,
                                                      const u64* __restrict__ cand_g,
                                                      const float4* __restrict__ cbox_g,
                                                      const u32* __restrict__ cnt_g,
                                                      float* __restrict__ out) {
    const int b    = blockIdx.x;
    const int tid  = threadIdx.x;
    const int wid  = tid >> 6;
    const int lane = tid & 63;

    __shared__ u64 sel[TOPK_K];                    // 8 KB
    alignas(16) __shared__ char SC[49152];         // 48 KB phase-reused
    __shared__ u64 keepm_s[16];
    __shared__ u64 wmin_s[16], wmax_s[16];
    __shared__ u64 kmin_s;
    __shared__ u32 shift_s;
    __shared__ u32 bcnt[256], bfill[256], bstart[257];
    __shared__ u32 cls_cnt[100], cls_start[100], cls_fill[100];
    __shared__ u32 binT_s, binT2_s, C1_s, cntS_s;

    u64* candS    = (u64*)SC;                      // [0,16K)
    u64* bucketed = (u64*)(SC + 16384);            // [16K,32K)
    u32* hist     = (u32*)(SC + 16384);            // [16K,48K) fallback only
    float* sx1 = (float*)SC;                       // [0,4K)   (after rank)
    float* sy1 = (float*)(SC + 4096);
    float* sx2 = (float*)(SC + 8192);
    float* sy2 = (float*)(SC + 12288);
    float* sar = (float*)(SC + 16384);             // [16K,20K) (after rank+bar)
    unsigned short* items = (unsigned short*)(SC + 20480);  // [20K,22K)
    float4* rbox = (float4*)(SC + 32768);          // [32K,48K)

    if (tid < 256) { bcnt[tid] = 0u; bfill[tid] = 0u; }
    if (tid < 100) { cls_cnt[tid] = 0u; cls_fill[tid] = 0u; }
    if (tid == 0) cntS_s = 0u;

    const u32 cnt = cnt_g[b << 5];
    const bool fast = (cnt >= TOPK_K && cnt <= CAND_CAP);
    int C;

    if (fast) {
        C = (int)cnt;
        for (int i = tid; i < C; i += 1024) candS[i] = cand_g[(b << 11) + i];
        __syncthreads();
    } else {
        // ---------------- FALLBACK: r5 two-level histogram select ----------
        const u64* K = keys + (size_t)b * N_DIM;
        for (int i = tid; i < 8192; i += 1024) hist[i] = 0u;
        __syncthreads();
        for (int n = tid * 2; n < N_DIM; n += 2048) {
            ulonglong2 k2 = *reinterpret_cast<const ulonglong2*>(K + n);
            atomicAdd(&hist[key_bin1(k2.x)], 1u);
            atomicAdd(&hist[key_bin1(k2.y)], 1u);
        }
        __syncthreads();
        if (wid == 0) scan_hist(hist, TOPK_K, &binT_s, &C1_s);
        __syncthreads();
        const u32 binT = binT_s;
        const u32 C1   = C1_s;
        __syncthreads();
        for (int i = tid; i < 8192; i += 1024) hist[i] = 0u;
        __syncthreads();
        for (int n = tid * 2; n < N_DIM; n += 2048) {
            ulonglong2 k2 = *reinterpret_cast<const ulonglong2*>(K + n);
            if (key_bin1(k2.x) == binT) atomicAdd(&hist[key_bin2(k2.x)], 1u);
            if (key_bin1(k2.y) == binT) atomicAdd(&hist[key_bin2(k2.y)], 1u);
        }
        __syncthreads();
        if (wid == 0) scan_hist(hist, TOPK_K - C1, &binT2_s, nullptr);
        __syncthreads();
        const u32 binT2 = binT2_s;
        __syncthreads();                           // hist dead
        for (int n = tid * 2; n < N_DIM; n += 2048) {
            ulonglong2 k2 = *reinterpret_cast<const ulonglong2*>(K + n);
            u32 b1x = key_bin1(k2.x);
            if (b1x > binT || (b1x == binT && key_bin2(k2.x) >= binT2)) {
                u32 p = atomicAdd(&cntS_s, 1u);
                if (p < CAND_CAP) candS[p] = k2.x;
            }
            u32 b1y = key_bin1(k2.y);
            if (b1y > binT || (b1y == binT && key_bin2(k2.y) >= binT2)) {
                u32 p = atomicAdd(&cntS_s, 1u);
                if (p < CAND_CAP) candS[p] = k2.y;
            }
        }
        __syncthreads();
        C = (int)cntS_s; if (C > CAND_CAP) C = CAND_CAP;
    }

    // ---- min/max over candidate keys ----
    u64 kmn = ~0ull, kmx = 0ull;
    for (int i = tid; i < C; i += 1024) {
        u64 k = candS[i];
        if (k < kmn) kmn = k;
        if (k > kmx) kmx = k;
    }
#pragma unroll
    for (int off = 32; off; off >>= 1) {
        u64 a = shfl_xor64(kmn, off); if (a < kmn) kmn = a;
        u64 m = shfl_xor64(kmx, off); if (m > kmx) kmx = m;
    }
    if (lane == 0) { wmin_s[wid] = kmn; wmax_s[wid] = kmx; }
    __syncthreads();
    if (tid == 0) {
        u64 mn = wmin_s[0], mx = wmax_s[0];
        for (int i = 1; i < 16; ++i) {
            if (wmin_s[i] < mn) mn = wmin_s[i];
            if (wmax_s[i] > mx) mx = wmax_s[i];
        }
        kmin_s = mn;
        u64 d = mx - mn;
        int pos = 63 - __clzll(d | 1ull);
        shift_s = (pos > 7) ? (u32)(pos - 7) : 0u;
    }
    __syncthreads();
    const u64 kmin = kmin_s;
    const u32 shift = shift_s;

    // ---- bucket histogram (exact, monotonic bucketing) ----
    const bool own0 = (tid < C);
    const bool own1 = (tid + 1024 < C);
    u64 key0 = 0, key1 = 0; u32 bkt0 = 0, bkt1 = 0;
    if (own0) { key0 = candS[tid];        bkt0 = (u32)((key0 - kmin) >> shift); atomicAdd(&bcnt[bkt0], 1u); }
    if (own1) { key1 = candS[tid + 1024]; bkt1 = (u32)((key1 - kmin) >> shift); atomicAdd(&bcnt[bkt1], 1u); }
    __syncthreads();
    if (wid == 0) {   // exclusive prefix over 256 bins
        u32 s0 = bcnt[lane * 4], s1 = bcnt[lane * 4 + 1],
            s2 = bcnt[lane * 4 + 2], s3 = bcnt[lane * 4 + 3];
        u32 tot = s0 + s1 + s2 + s3;
        u32 incl = tot;
#pragma unroll
        for (int off = 1; off < 64; off <<= 1) {
            u32 v = (u32)__shfl_up((int)incl, off);
            if (lane >= off) incl += v;
        }
        u32 ex = incl - tot;
        bstart[lane * 4]     = ex;
        bstart[lane * 4 + 1] = ex + s0;
        bstart[lane * 4 + 2] = ex + s0 + s1;
        bstart[lane * 4 + 3] = ex + s0 + s1 + s2;
        if (lane == 63) bstart[256] = incl;
    }
    __syncthreads();
    if (own0) { u32 p = bstart[bkt0] + atomicAdd(&bfill[bkt0], 1u); bucketed[p] = key0; }
    if (own1) { u32 p = bstart[bkt1] + atomicAdd(&bfill[bkt1], 1u); bucketed[p] = key1; }
    __syncthreads();

    // ---- exact rank within bucket + write rank-ordered NMS inputs ----
    u32 rank0 = ~0u, rank1 = ~0u; float area0 = 0.f, area1 = 0.f;
#define RANK_ONE(own, mykey, mybkt, slot, rankv, areav)                       \
    if (own) {                                                                \
        u32 lo = bstart[mybkt], hi = bstart[mybkt + 1];                       \
        u32 g = 0;                                                            \
        for (u32 p = lo; p < hi; ++p) g += (bucketed[p] > (mykey));           \
        u32 rk = ((u32)C - hi) + g;                                           \
        if (rk < TOPK_K) {                                                    \
            rankv = rk;                                                       \
            float4 bx;                                                        \
            if (fast) bx = cbox_g[(b << 11) + (slot)];                        \
            else {                                                            \
                int n = (N_DIM - 1) - (int)(((mykey) >> 7) & (u64)(N_DIM - 1)); \
                const float* row = pred + ((size_t)b * N_DIM + n) * ROW_F;    \
                bx = make_float4(row[0], row[1], row[2], row[3]);             \
            }                                                                 \
            int lab = (int)((mykey) & 0x7Full);                               \
            float x1 = bx.x - bx.z * 0.5f, y1 = bx.y - bx.w * 0.5f;           \
            float x2 = bx.z + x1,          y2 = bx.w + y1;                    \
            float off = (float)lab * OFFSET_F;                                \
            float nx1 = x1 + off, ny1 = y1 + off;                             \
            float nx2 = x2 + off, ny2 = y2 + off;                             \
            areav = (nx2 - nx1) * (ny2 - ny1);                                \
            sel[rk] = (mykey);                                                \
            sx1[rk] = nx1; sy1[rk] = ny1; sx2[rk] = nx2; sy2[rk] = ny2;       \
            rbox[rk] = make_float4(x1, y1, x2, y2);                           \
        }                                                                     \
    }
    RANK_ONE(own0, key0, bkt0, tid,        rank0, area0)
    RANK_ONE(own1, key1, bkt1, tid + 1024, rank1, area1)
#undef RANK_ONE
    __syncthreads();                               // bucketed dead
    if (rank0 != ~0u) sar[rank0] = area0;
    if (rank1 != ~0u) sar[rank1] = area1;

    // ---- per-rank decode + class lists ----
    u64 key = sel[tid];
    int lab = (int)(key & 0x7Full);
    u32 ou  = (u32)(key >> 22);
    u32 ob  = (ou & 0x80000000u) ? (ou & 0x7FFFFFFFu) : ~ou;
    float score = __uint_as_float(ob);
    bool validk = (score >= 0.0f);
    atomicAdd(&cls_cnt[lab], 1u);
    __syncthreads();
    if (wid == 0) {   // exclusive prefix over 100 class bins
        u32 s0 = (lane < 50) ? cls_cnt[lane * 2] : 0u;
        u32 s1 = (lane < 50) ? cls_cnt[lane * 2 + 1] : 0u;
        u32 tot = s0 + s1;
        u32 incl = tot;
#pragma unroll
        for (int off = 1; off < 64; off <<= 1) {
            u32 v = (u32)__shfl_up((int)incl, off);
            if (lane >= off) incl += v;
        }
        u32 ex = incl - tot;
        if (lane < 50) { cls_start[lane * 2] = ex; cls_start[lane * 2 + 1] = ex + s0; }
    }
    __syncthreads();
    {
        u32 p = cls_start[lab] + atomicAdd(&cls_fill[lab], 1u);
        items[p] = (unsigned short)tid;
    }
    __syncthreads();

    const float nx1 = sx1[tid], ny1 = sy1[tid], nx2 = sx2[tid], ny2 = sy2[tid];
    const float area = sar[tid];

    // ---- suppression-mask column, same-class partners only (~10 IoUs) ----
    // Cross-class IoU is exactly 0 (class offset 241 >= extent bound 231).
    u64 m0=0,m1=0,m2=0,m3=0,m4=0,m5=0,m6=0,m7=0,
        m8=0,m9=0,m10=0,m11=0,m12=0,m13=0,m14=0,m15=0;
    {
        const int s0 = (int)cls_start[lab];
        const int e0 = s0 + (int)cls_cnt[lab];
        for (int p = s0; p < e0; ++p) {
            int i = (int)items[p];
            if (i == tid) continue;
            float ix1 = fmaxf(sx1[i], nx1), iy1 = fmaxf(sy1[i], ny1);
            float ix2 = fminf(sx2[i], nx2), iy2 = fminf(sy2[i], ny2);
            float iw = fmaxf(ix2 - ix1, 0.0f), ih = fmaxf(iy2 - iy1, 0.0f);
            float inter = iw * ih;
            float iou = inter / (sar[i] + area - inter + 1e-12f);
            if (iou > NMS_THRE_F) {
                u64 bit = 1ull << (i & 63);
                int ch = i >> 6;
                m0  |= (ch == 0)  ? bit : 0ull;  m1  |= (ch == 1)  ? bit : 0ull;
                m2  |= (ch == 2)  ? bit : 0ull;  m3  |= (ch == 3)  ? bit : 0ull;
                m4  |= (ch == 4)  ? bit : 0ull;  m5  |= (ch == 5)  ? bit : 0ull;
                m6  |= (ch == 6)  ? bit : 0ull;  m7  |= (ch == 7)  ? bit : 0ull;
                m8  |= (ch == 8)  ? bit : 0ull;  m9  |= (ch == 9)  ? bit : 0ull;
                m10 |= (ch == 10) ? bit : 0ull;  m11 |= (ch == 11) ? bit : 0ull;
                m12 |= (ch == 12) ? bit : 0ull;  m13 |= (ch == 13) ? bit : 0ull;
                m14 |= (ch == 14) ? bit : 0ull;  m15 |= (ch == 15) ? bit : 0ull;
            }
        }
    }

    // ---- greedy scan, 16 chunks; serial work only on conflicted lanes ----
    bool supp = false, keepb = false;
#define CHUNK_STEP(c, mc)                                                     \
    {                                                                         \
        if (wid == (c)) {                                                     \
            u64 W  = (mc);                                                    \
            u64 vm = __ballot(validk && !supp);                               \
            u64 S  = __ballot(W != 0ull);                                     \
            u64 km = vm & ~S;                                                 \
            u64 suppm = 0ull, mm = S;                                         \
            while (mm) {                                                      \
                int i = __builtin_ctzll(mm); mm &= mm - 1ull;                 \
                u64 Wi = shfl64(W, i);                                        \
                if (((vm >> i) & 1ull) && !((suppm >> i) & 1ull)) {           \
                    km |= 1ull << i; suppm |= Wi;                             \
                }                                                             \
            }                                                                 \
            keepb = ((km >> lane) & 1ull) != 0ull;                            \
            if (lane == 0) keepm_s[(c)] = km;                                 \
        }                                                                     \
        __syncthreads();                                                      \
        if (wid > (c) && ((mc) & keepm_s[(c)])) supp = true;                  \
    }
    CHUNK_STEP(0, m0)   CHUNK_STEP(1, m1)   CHUNK_STEP(2, m2)   CHUNK_STEP(3, m3)
    CHUNK_STEP(4, m4)   CHUNK_STEP(5, m5)   CHUNK_STEP(6, m6)   CHUNK_STEP(7, m7)
    CHUNK_STEP(8, m8)   CHUNK_STEP(9, m9)   CHUNK_STEP(10, m10) CHUNK_STEP(11, m11)
    CHUNK_STEP(12, m12) CHUNK_STEP(13, m13) CHUNK_STEP(14, m14) CHUNK_STEP(15, m15)
#undef CHUNK_STEP

    float keepf = keepb ? 1.0f : 0.0f;
    float4 rb4 = rbox[tid];
    float2* o2 = (float2*)(out + ((size_t)b * TOPK_K + tid) * 6);
    o2[0] = make_float2(rb4.x * keepf, rb4.y * keepf);
    o2[1] = make_float2(rb4.z * keepf, rb4.w * keepf);
    o2[2] = make_float2(score * keepf, (float)lab * keepf);
}

// ---------------------------------------------------------------------------
extern "C" void kernel_launch(void* const* d_in, const int* in_sizes, int n_in,
                              void* d_out, int out_size, void* d_ws, size_t ws_size,
                              hipStream_t stream) {
    const float* pred = (const float*)d_in[0];
    float* out = (float*)d_out;

    // workspace layout
    u64*    keys = (u64*)d_ws;                                       // 2 MB
    u64*    cand = (u64*)((char*)d_ws + (2u << 20));                 // 128 KB
    float4* cbox = (float4*)((char*)d_ws + (2u << 20) + (128u << 10)); // 256 KB
    u32*    cnt  = (u32*)((char*)d_ws + (2u << 20) + (384u << 10));  // 1 KB

    hipMemsetAsync(cnt, 0, B_DIM * 32 * sizeof(u32), stream);
    decode_kernel<<<(B_DIM * N_DIM) / 256, 256, 0, stream>>>(pred, keys, cand, cbox, cnt);
    selnms_kernel<<<B_DIM, 1024, 0, stream>>>(pred, keys, cand, cbox, cnt, out);
}